// Round 1
// baseline (2453.202 us; speedup 1.0000x reference)
//
#include <hip/hip_runtime.h>
#include <math.h>
#include <type_traits>

#define DMODEL 1024
#define NSEQ   4096
#define NBATCH 4
#define MTOT   (NBATCH*NSEQ)   // 16384

constexpr int BM = 128, BN = 128, BK = 8, TM = 8, TN = 8;
// block: 16x16 = 256 threads, each computes an 8x8 micro-tile

enum { MODE_PLAIN = 0, MODE_GELU_BIAS = 1, MODE_BIAS = 2, MODE_CONCAT_GELU_BIAS = 3 };

__device__ __forceinline__ float gelu_f(float x) {
    return 0.5f * x * (1.0f + erff(x * 0.70710678118654752440f));
}
__device__ __forceinline__ double gelu_d(double x) {
    return 0.5 * x * (1.0 + erf(x * 0.70710678118654752440));
}

// C = op(A @ B [+ bias]) ; A row-major [M,K], B row-major [K,N].
// MODE_CONCAT_GELU_BIAS: A is V [MTOT, DMODEL]; for k >= DMODEL the A row is
// V[gidx[m]] (per-token gather), col k-DMODEL.  DACC => fp64 accumulate, C is double*.
template<int MODE, bool DACC>
__global__ __launch_bounds__(256)
void gemm_k(const float* __restrict__ A, const float* __restrict__ B,
            const float* __restrict__ bias, void* __restrict__ Cv,
            int M, int N, int K, const int* __restrict__ gidx)
{
    __shared__ float As[BK][BM + 4];
    __shared__ float Bs[BK][BN + 4];

    const int tid = threadIdx.x;
    const int tx = tid & 15, ty = tid >> 4;
    const int m0 = blockIdx.y * BM;
    const int n0 = blockIdx.x * BN;

    // A-tile loader: 128 rows x 8 cols = 1024 floats, float4 per thread
    const int ar = tid >> 1;            // 0..127
    const int ac = (tid & 1) * 4;       // 0 or 4
    // B-tile loader: 8 rows x 128 cols, float4 per thread
    const int bkr = tid >> 5;           // 0..7
    const int bc  = (tid & 31) * 4;     // 0..124

    const int astride = (MODE == MODE_CONCAT_GELU_BIAS) ? DMODEL : K;
    const float* Arow = A + (size_t)(m0 + ar) * astride;
    const float* Arow2 = nullptr;
    if constexpr (MODE == MODE_CONCAT_GELU_BIAS) {
        Arow2 = A + (size_t)gidx[m0 + ar] * DMODEL;
    }

    using AccT = typename std::conditional<DACC, double, float>::type;
    AccT acc[TM][TN];
    #pragma unroll
    for (int i = 0; i < TM; i++)
        #pragma unroll
        for (int j = 0; j < TN; j++) acc[i][j] = (AccT)0;

    for (int kk = 0; kk < K; kk += BK) {
        const float* ap;
        if constexpr (MODE == MODE_CONCAT_GELU_BIAS) {
            ap = (kk < DMODEL) ? (Arow + kk + ac) : (Arow2 + (kk - DMODEL) + ac);
        } else {
            ap = Arow + kk + ac;
        }
        float4 av = *(const float4*)ap;
        As[ac + 0][ar] = av.x; As[ac + 1][ar] = av.y;
        As[ac + 2][ar] = av.z; As[ac + 3][ar] = av.w;
        float4 bv = *(const float4*)(B + (size_t)(kk + bkr) * N + n0 + bc);
        *(float4*)&Bs[bkr][bc] = bv;
        __syncthreads();

        #pragma unroll
        for (int k = 0; k < BK; k++) {
            float a[TM], b[TN];
            *(float4*)&a[0] = *(const float4*)&As[k][ty * TM];
            *(float4*)&a[4] = *(const float4*)&As[k][ty * TM + 4];
            *(float4*)&b[0] = *(const float4*)&Bs[k][tx * TN];
            *(float4*)&b[4] = *(const float4*)&Bs[k][tx * TN + 4];
            #pragma unroll
            for (int i = 0; i < TM; i++)
                #pragma unroll
                for (int j = 0; j < TN; j++) {
                    if constexpr (DACC)
                        acc[i][j] = fma((double)a[i], (double)b[j], acc[i][j]);
                    else
                        acc[i][j] = fmaf(a[i], b[j], acc[i][j]);
                }
        }
        __syncthreads();
    }

    const int crow = m0 + ty * TM;
    const int ccol = n0 + tx * TN;
    if constexpr (DACC) {
        double* C = (double*)Cv;
        #pragma unroll
        for (int i = 0; i < TM; i++)
            #pragma unroll
            for (int j = 0; j < TN; j++) {
                double v = acc[i][j] + (double)bias[ccol + j];
                v = gelu_d(v);
                C[(size_t)(crow + i) * N + ccol + j] = v;
            }
    } else {
        float* C = (float*)Cv;
        #pragma unroll
        for (int i = 0; i < TM; i++) {
            float vals[TN];
            #pragma unroll
            for (int j = 0; j < TN; j++) {
                float v = acc[i][j];
                if constexpr (MODE == MODE_GELU_BIAS || MODE == MODE_BIAS ||
                              MODE == MODE_CONCAT_GELU_BIAS)
                    v += bias[ccol + j];
                if constexpr (MODE == MODE_GELU_BIAS || MODE == MODE_CONCAT_GELU_BIAS)
                    v = gelu_f(v);
                vals[j] = v;
            }
            float* cp = C + (size_t)(crow + i) * N + ccol;
            *(float4*)cp       = make_float4(vals[0], vals[1], vals[2], vals[3]);
            *(float4*)(cp + 4) = make_float4(vals[4], vals[5], vals[6], vals[7]);
        }
    }
}

// logits -> sigmoid -> round-half-even targets (+ strength, target float, gather idx)
// one wave per token; fp64 throughout to track the true value
__global__ __launch_bounds__(256)
void target_k(const double* __restrict__ H, const float* __restrict__ W2,
              const float* __restrict__ b2, float* __restrict__ outT,
              float* __restrict__ outS, int* __restrict__ gidx)
{
    const int m = blockIdx.x * 4 + (threadIdx.x >> 6);
    const int lane = threadIdx.x & 63;
    const double* hr = H + (size_t)m * 512;
    double s = 0.0;
    #pragma unroll 4
    for (int j = lane; j < 512; j += 64) s = fma(hr[j], (double)W2[j], s);
    #pragma unroll
    for (int off = 32; off; off >>= 1) s += __shfl_down(s, off);
    if (lane == 0) {
        double logit = s + (double)b2[0];
        double str = 1.0 / (1.0 + exp(-logit));
        double r = rint(str * (double)(NSEQ - 1));   // round half-to-even, like np.round
        r = fmin(fmax(r, 0.0), (double)(NSEQ - 1));
        int t = (int)r;
        outT[m] = (float)t;
        outS[m] = (float)str;
        gidx[m] = ((m >> 12) << 12) + t;   // global row = b*NSEQ + t
    }
}

// b_c[j] = sum_e b_rt2[e] * W_o[e,j]
__global__ __launch_bounds__(256)
void biascomb_k(const float* __restrict__ brt2, const float* __restrict__ Wo,
                float* __restrict__ bc)
{
    int j = blockIdx.x * 256 + threadIdx.x;   // 0..1023
    float s = 0.f;
    for (int e = 0; e < DMODEL; e++) s = fmaf(brt2[e], Wo[e * DMODEL + j], s);
    bc[j] = s;
}

extern "C" void kernel_launch(void* const* d_in, const int* in_sizes, int n_in,
                              void* d_out, int out_size, void* d_ws, size_t ws_size,
                              hipStream_t stream)
{
    const float* h     = (const float*)d_in[0];
    const float* W_re1 = (const float*)d_in[1];
    const float* b_re1 = (const float*)d_in[2];
    const float* W_re2 = (const float*)d_in[3];
    const float* b_re2 = (const float*)d_in[4];
    const float* W_v   = (const float*)d_in[5];
    const float* W_rt1 = (const float*)d_in[6];
    const float* b_rt1 = (const float*)d_in[7];
    const float* W_rt2 = (const float*)d_in[8];
    const float* b_rt2 = (const float*)d_in[9];
    const float* W_o   = (const float*)d_in[10];

    float* z    = (float*)d_out;                       // [16384,1024]
    float* outT = z + (size_t)MTOT * DMODEL;           // [16384] targets (as float)
    float* outS = outT + MTOT;                         // [16384] strength

    char* ws = (char*)d_ws;
    float*  G    = (float*)ws;                                      // 64 MB
    double* Hd   = (double*)(ws + (size_t)64 * 1024 * 1024);        // 64 MB
    float*  W_c  = (float*)(ws + (size_t)128 * 1024 * 1024);        // 4 MB
    float*  b_c  = (float*)(ws + (size_t)132 * 1024 * 1024);        // 4 KB
    int*    gidx = (int*)  (ws + (size_t)132 * 1024 * 1024 + 4096); // 64 KB

    float* V = z;   // z region doubles as scratch for V; dead before final GEMM writes z

    // W_c = W_rt2 @ W_o (fold the last two projections), b_c = b_rt2 @ W_o
    gemm_k<MODE_PLAIN, false><<<dim3(8, 8), 256, 0, stream>>>(
        W_rt2, W_o, nullptr, (void*)W_c, DMODEL, DMODEL, DMODEL, nullptr);
    biascomb_k<<<dim3(4), 256, 0, stream>>>(b_rt2, W_o, b_c);

    // H = gelu(h @ W_re1 + b_re1), fp64 accumulate (target indices must be exact)
    gemm_k<MODE_GELU_BIAS, true><<<dim3(4, 128), 256, 0, stream>>>(
        h, W_re1, b_re1, (void*)Hd, MTOT, 512, DMODEL, nullptr);

    // strength / targets / gather indices
    target_k<<<dim3(MTOT / 4), 256, 0, stream>>>(Hd, W_re2, b_re2, outT, outS, gidx);

    // V = h @ W_v   (gather commutes with W_v: target_values = gather(V))
    gemm_k<MODE_PLAIN, false><<<dim3(8, 128), 256, 0, stream>>>(
        h, W_v, nullptr, (void*)V, MTOT, DMODEL, DMODEL, nullptr);

    // G = gelu([V | gather(V)] @ W_rt1 + b_rt1)
    gemm_k<MODE_CONCAT_GELU_BIAS, false><<<dim3(8, 128), 256, 0, stream>>>(
        V, W_rt1, b_rt1, (void*)G, MTOT, DMODEL, 2 * DMODEL, gidx);

    // z = G @ W_c + b_c
    gemm_k<MODE_BIAS, false><<<dim3(8, 128), 256, 0, stream>>>(
        G, W_c, b_c, (void*)z, MTOT, DMODEL, DMODEL, nullptr);
}

// Round 2
// 1006.994 us; speedup vs baseline: 2.4362x; 2.4362x over previous
//
#include <hip/hip_runtime.h>
#include <math.h>
#include <type_traits>

#define DMODEL 1024
#define NSEQ   4096
#define MTOT   16384

typedef unsigned short ushortT;
typedef __attribute__((ext_vector_type(8))) short short8;
typedef __attribute__((ext_vector_type(4))) float f32x4;

__device__ __forceinline__ float gelu_f(float x) {
    return 0.5f * x * (1.0f + erff(x * 0.70710678118654752440f));
}
__device__ __forceinline__ double gelu_d(double x) {
    return 0.5 * x * (1.0 + erf(x * 0.70710678118654752440));
}
__device__ __forceinline__ ushortT f2bf(float f) {
    unsigned u = __float_as_uint(f);
    u += 0x7FFFu + ((u >> 16) & 1u);   // round-to-nearest-even
    return (ushortT)(u >> 16);
}
// async global->LDS, 16B per lane; LDS dest = wave-uniform base + lane*16
__device__ __forceinline__ void gload16(const void* g, void* l) {
    __builtin_amdgcn_global_load_lds(
        (const __attribute__((address_space(1))) unsigned*)g,
        (__attribute__((address_space(3))) unsigned*)l, 16, 0, 0);
}

// ---------------- bf16 MFMA GEMM (m97 structure) ----------------
// C = epi(A @ Bt^T [+bias]); A [M,K] bf16 row-major (lda), Bt [N,K] bf16 (ldb).
// GATHER: A is V [MTOT,DMODEL]; logical K=2*DMODEL, k>=DMODEL reads row gidx[m].
enum { EPI_BF16 = 0, EPI_GELU_BIAS_BF16 = 1, EPI_BIAS_F32 = 2, EPI_TRANS_BF16 = 3 };

template<int EPI, bool GATHER>
__global__ __launch_bounds__(256)
void mfma_gemm(const ushortT* __restrict__ A, const ushortT* __restrict__ Bt,
               const float* __restrict__ bias, void* __restrict__ Cv,
               int K, int lda, int ldb, int ldc, const int* __restrict__ gidx)
{
    __shared__ ushortT As[128 * 32];
    __shared__ ushortT Bs[128 * 32];
    const int tid  = threadIdx.x;
    const int lane = tid & 63;
    const int w    = tid >> 6;
    const int wr   = (w >> 1) * 64;   // wave row offset in tile
    const int wc   = (w & 1) * 64;    // wave col offset in tile
    const int m0   = blockIdx.y * 128;
    const int n0   = blockIdx.x * 128;

    const int lrow = lane >> 2;        // 0..15 row within 16-row staging group
    const int lk   = (lane & 3) * 8;   // k elem offset of this lane's 16B

    int grow_g[2];
    if constexpr (GATHER) {
        grow_g[0] = gidx[m0 + w * 32 + lrow];
        grow_g[1] = gidx[m0 + w * 32 + 16 + lrow];
    }

    f32x4 acc[4][4];
    #pragma unroll
    for (int i = 0; i < 4; i++)
        #pragma unroll
        for (int j = 0; j < 4; j++) acc[i][j] = (f32x4){0.f, 0.f, 0.f, 0.f};

    for (int kk = 0; kk < K; kk += 32) {
        #pragma unroll
        for (int i = 0; i < 2; i++) {
            const int ar = w * 32 + i * 16 + lrow;
            const ushortT* ga;
            if constexpr (GATHER) {
                ga = (kk < DMODEL)
                   ? A + (size_t)(m0 + ar) * lda + kk + lk
                   : A + (size_t)grow_g[i] * lda + (kk - DMODEL) + lk;
            } else {
                ga = A + (size_t)(m0 + ar) * lda + kk + lk;
            }
            gload16(ga, &As[(w * 32 + i * 16) * 32]);
            const ushortT* gb = Bt + (size_t)(n0 + w * 32 + i * 16 + lrow) * ldb + kk + lk;
            gload16(gb, &Bs[(w * 32 + i * 16) * 32]);
        }
        __syncthreads();

        const int mi = lane & 15;
        const int ko = (lane >> 4) * 8;
        short8 a[4], b[4];
        #pragma unroll
        for (int i = 0; i < 4; i++)
            a[i] = *(const short8*)&As[(wr + i * 16 + mi) * 32 + ko];
        #pragma unroll
        for (int j = 0; j < 4; j++)
            b[j] = *(const short8*)&Bs[(wc + j * 16 + mi) * 32 + ko];
        #pragma unroll
        for (int i = 0; i < 4; i++)
            #pragma unroll
            for (int j = 0; j < 4; j++)
                acc[i][j] = __builtin_amdgcn_mfma_f32_16x16x32_bf16(a[i], b[j], acc[i][j], 0, 0, 0);
        __syncthreads();
    }

    // epilogue: C/D layout col=lane&15, row=(lane>>4)*4+reg  [m89/m91]
    const int cr = (lane >> 4) * 4;
    const int cc = lane & 15;
    #pragma unroll
    for (int i = 0; i < 4; i++) {
        #pragma unroll
        for (int j = 0; j < 4; j++) {
            const int gr = m0 + wr + i * 16 + cr;
            const int gc = n0 + wc + j * 16 + cc;
            #pragma unroll
            for (int r = 0; r < 4; r++) {
                float v = acc[i][j][r];
                if constexpr (EPI == EPI_GELU_BIAS_BF16) v = gelu_f(v + bias[gc]);
                if constexpr (EPI == EPI_BIAS_F32)       v = v + bias[gc];
                if constexpr (EPI == EPI_BF16 || EPI == EPI_GELU_BIAS_BF16)
                    ((ushortT*)Cv)[(size_t)(gr + r) * ldc + gc] = f2bf(v);
                else if constexpr (EPI == EPI_BIAS_F32)
                    ((float*)Cv)[(size_t)(gr + r) * ldc + gc] = v;
                else
                    ((ushortT*)Cv)[(size_t)gc * ldc + (gr + r)] = f2bf(v);  // store C^T
            }
        }
    }
}

// ---------------- fp64-accumulate encoder GEMM (unchanged, exactness-critical) ----
constexpr int BM = 128, BN = 128, BK = 8, TM = 8, TN = 8;

__global__ __launch_bounds__(256)
void gemm_f64_gelu(const float* __restrict__ A, const float* __restrict__ B,
                   const float* __restrict__ bias, double* __restrict__ C,
                   int M, int N, int K)
{
    __shared__ float As[BK][BM + 4];
    __shared__ float Bs[BK][BN + 4];
    const int tid = threadIdx.x;
    const int tx = tid & 15, ty = tid >> 4;
    const int m0 = blockIdx.y * BM;
    const int n0 = blockIdx.x * BN;
    const int ar = tid >> 1;
    const int ac = (tid & 1) * 4;
    const int bkr = tid >> 5;
    const int bc  = (tid & 31) * 4;
    const float* Arow = A + (size_t)(m0 + ar) * K;

    double acc[TM][TN];
    #pragma unroll
    for (int i = 0; i < TM; i++)
        #pragma unroll
        for (int j = 0; j < TN; j++) acc[i][j] = 0.0;

    for (int kk = 0; kk < K; kk += BK) {
        float4 av = *(const float4*)(Arow + kk + ac);
        As[ac + 0][ar] = av.x; As[ac + 1][ar] = av.y;
        As[ac + 2][ar] = av.z; As[ac + 3][ar] = av.w;
        float4 bv = *(const float4*)(B + (size_t)(kk + bkr) * N + n0 + bc);
        *(float4*)&Bs[bkr][bc] = bv;
        __syncthreads();
        #pragma unroll
        for (int k = 0; k < BK; k++) {
            float a[TM], b[TN];
            *(float4*)&a[0] = *(const float4*)&As[k][ty * TM];
            *(float4*)&a[4] = *(const float4*)&As[k][ty * TM + 4];
            *(float4*)&b[0] = *(const float4*)&Bs[k][tx * TN];
            *(float4*)&b[4] = *(const float4*)&Bs[k][tx * TN + 4];
            #pragma unroll
            for (int i = 0; i < TM; i++)
                #pragma unroll
                for (int j = 0; j < TN; j++)
                    acc[i][j] = fma((double)a[i], (double)b[j], acc[i][j]);
        }
        __syncthreads();
    }
    const int crow = m0 + ty * TM;
    const int ccol = n0 + tx * TN;
    #pragma unroll
    for (int i = 0; i < TM; i++)
        #pragma unroll
        for (int j = 0; j < TN; j++)
            C[(size_t)(crow + i) * N + ccol + j] = gelu_d(acc[i][j] + (double)bias[ccol + j]);
}

// logits -> sigmoid -> round-half-even targets; fp64 (exactness-critical)
__global__ __launch_bounds__(256)
void target_k(const double* __restrict__ H, const float* __restrict__ W2,
              const float* __restrict__ b2, float* __restrict__ outT,
              float* __restrict__ outS, int* __restrict__ gidx)
{
    const int m = blockIdx.x * 4 + (threadIdx.x >> 6);
    const int lane = threadIdx.x & 63;
    const double* hr = H + (size_t)m * 512;
    double s = 0.0;
    #pragma unroll 4
    for (int j = lane; j < 512; j += 64) s = fma(hr[j], (double)W2[j], s);
    #pragma unroll
    for (int off = 32; off; off >>= 1) s += __shfl_down(s, off);
    if (lane == 0) {
        double logit = s + (double)b2[0];
        double str = 1.0 / (1.0 + exp(-logit));
        double r = rint(str * (double)(NSEQ - 1));
        r = fmin(fmax(r, 0.0), (double)(NSEQ - 1));
        int t = (int)r;
        outT[m] = (float)t;
        outS[m] = (float)str;
        gidx[m] = ((m >> 12) << 12) + t;
    }
}

__global__ __launch_bounds__(256)
void biascomb_k(const float* __restrict__ brt2, const float* __restrict__ Wo,
                float* __restrict__ bc)
{
    int j = blockIdx.x * 256 + threadIdx.x;
    float s = 0.f;
    for (int e = 0; e < DMODEL; e++) s = fmaf(brt2[e], Wo[e * DMODEL + j], s);
    bc[j] = s;
}

// f32 -> bf16 straight cast, 4 elems/thread
__global__ __launch_bounds__(256)
void cast_k(const float* __restrict__ x, ushortT* __restrict__ y, int n)
{
    int i = (blockIdx.x * 256 + threadIdx.x) * 4;
    if (i < n) {
        float4 v = *(const float4*)(x + i);
        ushortT o[4] = { f2bf(v.x), f2bf(v.y), f2bf(v.z), f2bf(v.w) };
        *(ulong1*)&y[i] = *(ulong1*)o;
    }
}

// W [K][N] f32 -> Wt [N][K] bf16 (32x32 LDS tile transpose)
__global__ __launch_bounds__(256)
void transcast_k(const float* __restrict__ W, ushortT* __restrict__ Wt, int K, int N)
{
    __shared__ float t[32][33];
    const int tx = threadIdx.x & 31, ty = threadIdx.x >> 5;
    const int n0 = blockIdx.x * 32, k0 = blockIdx.y * 32;
    #pragma unroll
    for (int r = 0; r < 32; r += 8)
        t[ty + r][tx] = W[(size_t)(k0 + ty + r) * N + n0 + tx];
    __syncthreads();
    #pragma unroll
    for (int r = 0; r < 32; r += 8)
        Wt[(size_t)(n0 + ty + r) * K + k0 + tx] = f2bf(t[tx][ty + r]);
}

extern "C" void kernel_launch(void* const* d_in, const int* in_sizes, int n_in,
                              void* d_out, int out_size, void* d_ws, size_t ws_size,
                              hipStream_t stream)
{
    const float* h     = (const float*)d_in[0];
    const float* W_re1 = (const float*)d_in[1];
    const float* b_re1 = (const float*)d_in[2];
    const float* W_re2 = (const float*)d_in[3];
    const float* b_re2 = (const float*)d_in[4];
    const float* W_v   = (const float*)d_in[5];
    const float* W_rt1 = (const float*)d_in[6];
    const float* b_rt1 = (const float*)d_in[7];
    const float* W_rt2 = (const float*)d_in[8];
    const float* b_rt2 = (const float*)d_in[9];
    const float* W_o   = (const float*)d_in[10];

    float* z    = (float*)d_out;                 // [16384,1024] f32
    float* outT = z + (size_t)MTOT * DMODEL;
    float* outS = outT + MTOT;
    // dead-region reuse inside d_out's z block (fully rewritten by final GEMM):
    ushortT* V  = (ushortT*)z;                          // bf16, 32 MB
    ushortT* hb = (ushortT*)z + (size_t)MTOT * DMODEL;  // bf16, upper 32 MB

    char* ws = (char*)d_ws;
    double*  Hd     = (double*)ws;                           // 64 MB
    ushortT* G      = (ushortT*)(ws + (64ull  << 20));       // 32 MB
    ushortT* Wv_t   = (ushortT*)(ws + (96ull  << 20));       // 2 MB [1024][1024]
    ushortT* Wrt1_t = (ushortT*)(ws + (98ull  << 20));       // 4 MB [1024][2048]
    ushortT* Wo_t   = (ushortT*)(ws + (102ull << 20));       // 2 MB [1024][1024]
    ushortT* Wrt2_b = (ushortT*)(ws + (104ull << 20));       // 2 MB [1024][1024]
    ushortT* Wc_t   = (ushortT*)(ws + (106ull << 20));       // 2 MB [1024][1024]
    float*   b_c    = (float*)(ws + (108ull << 20));
    int*     gidx   = (int*)(ws + (108ull << 20) + 4096);

    // --- casts / transposes (cheap) ---
    cast_k<<<dim3(MTOT * DMODEL / 1024), 256, 0, stream>>>(h, hb, MTOT * DMODEL);
    cast_k<<<dim3(DMODEL * DMODEL / 1024), 256, 0, stream>>>(W_rt2, Wrt2_b, DMODEL * DMODEL);
    transcast_k<<<dim3(32, 32), 256, 0, stream>>>(W_v, Wv_t, DMODEL, DMODEL);
    transcast_k<<<dim3(32, 64), 256, 0, stream>>>(W_rt1, Wrt1_t, 2 * DMODEL, DMODEL);
    transcast_k<<<dim3(32, 32), 256, 0, stream>>>(W_o, Wo_t, DMODEL, DMODEL);
    biascomb_k<<<dim3(4), 256, 0, stream>>>(b_rt2, W_o, b_c);

    // --- encoder path, fp64 (targets must match exactly) ---
    gemm_f64_gelu<<<dim3(4, 128), 256, 0, stream>>>(h, W_re1, b_re1, Hd, MTOT, 512, DMODEL);
    target_k<<<dim3(MTOT / 4), 256, 0, stream>>>(Hd, W_re2, b_re2, outT, outS, gidx);

    // --- Wc_t = (W_rt2 @ W_o)^T bf16 (fold last two projections) ---
    mfma_gemm<EPI_TRANS_BF16, false><<<dim3(8, 8), 256, 0, stream>>>(
        Wrt2_b, Wo_t, nullptr, (void*)Wc_t, DMODEL, DMODEL, DMODEL, DMODEL, nullptr);

    // --- V = h @ W_v (bf16 out; gather commutes with W_v) ---
    mfma_gemm<EPI_BF16, false><<<dim3(8, 128), 256, 0, stream>>>(
        hb, Wv_t, nullptr, (void*)V, DMODEL, DMODEL, DMODEL, DMODEL, nullptr);

    // --- G = gelu([V | gather(V)] @ W_rt1 + b_rt1) ---
    mfma_gemm<EPI_GELU_BIAS_BF16, true><<<dim3(8, 128), 256, 0, stream>>>(
        V, Wrt1_t, b_rt1, (void*)G, 2 * DMODEL, DMODEL, 2 * DMODEL, DMODEL, gidx);

    // --- z = G @ W_c + b_c (f32 out) ---
    mfma_gemm<EPI_BIAS_F32, false><<<dim3(8, 128), 256, 0, stream>>>(
        G, Wc_t, b_c, (void*)z, DMODEL, DMODEL, DMODEL, DMODEL, nullptr);
}